// Round 2
// baseline (364.350 us; speedup 1.0000x reference)
//
#include <hip/hip_runtime.h>
#include <math.h>

// Problem constants (from reference): B=64, T=4096, H=256, all fp32.
constexpr int B_ = 64;
constexpr int T_ = 4096;
constexpr int H_ = 256;

constexpr int CHUNKS = 16;                      // T-chunks per batch row
constexpr int ROWS_PER_CHUNK = T_ / CHUNKS;     // 256
constexpr int WAVES = 4;                        // 256-thread block = 4 waves
constexpr int ROWS_PER_WAVE = ROWS_PER_CHUNK / WAVES;  // 64
constexpr int NBLK = B_ * CHUNKS;               // 1024 blocks = 4 blocks/CU

// Fused pass: scores + online softmax + weighted accumulation, single HBM read
// of token_embeddings. Each wave: 64 rows; lane l holds columns [4l, 4l+4).
// 8-row unroll: 8 KB of global loads in flight per wave, 8 interleaved
// shuffle-reduce chains.
__global__ __launch_bounds__(256) void pool_pass1(
    const float* __restrict__ emb, const float* __restrict__ mask,
    const float* __restrict__ query, float* __restrict__ ws_acc,
    float* __restrict__ ws_m, float* __restrict__ ws_l)
{
    const int blk  = blockIdx.x;
    const int b    = blk >> 4;            // / CHUNKS
    const int c    = blk & (CHUNKS - 1);
    const int wave = threadIdx.x >> 6;
    const int lane = threadIdx.x & 63;

    const float4 q = ((const float4*)query)[lane];
    const int row0 = c * ROWS_PER_CHUNK + wave * ROWS_PER_WAVE;
    const float4* src  = (const float4*)emb + (size_t)(b * T_ + row0) * (H_ / 4) + lane;
    const float*  mrow = mask + (size_t)b * T_ + row0;

    // Online-softmax state. Sentinel -1e30 (not -inf) keeps exp(m - m_new)
    // finite even before any unmasked row is seen.
    float  m = -1e30f, l = 0.f;
    float4 acc = make_float4(0.f, 0.f, 0.f, 0.f);

    for (int r = 0; r < ROWS_PER_WAVE; r += 8) {
        float4 v[8];
        float  s[8];
        #pragma unroll
        for (int i = 0; i < 8; ++i) v[i] = src[(size_t)(r + i) * 64];
        #pragma unroll
        for (int i = 0; i < 8; ++i)
            s[i] = v[i].x * q.x + v[i].y * q.y + v[i].z * q.z + v[i].w * q.w;

        // wave64 allreduce, 8 interleaved chains
        #pragma unroll
        for (int off = 32; off; off >>= 1) {
            #pragma unroll
            for (int i = 0; i < 8; ++i) s[i] += __shfl_xor(s[i], off, 64);
        }

        // mask==0 -> -inf  (exp gives exact 0 below)
        #pragma unroll
        for (int i = 0; i < 8; ++i)
            if (mrow[r + i] == 0.f) s[i] = -INFINITY;

        float m_new = m;
        #pragma unroll
        for (int i = 0; i < 8; ++i) m_new = fmaxf(m_new, s[i]);

        const float scale = __expf(m - m_new);
        float p[8];
        #pragma unroll
        for (int i = 0; i < 8; ++i) p[i] = __expf(s[i] - m_new);

        float lsum = 0.f;
        #pragma unroll
        for (int i = 0; i < 8; ++i) lsum += p[i];
        l = l * scale + lsum;

        float ax = acc.x * scale, ay = acc.y * scale,
              az = acc.z * scale, aw = acc.w * scale;
        #pragma unroll
        for (int i = 0; i < 8; ++i) {
            ax += p[i] * v[i].x;
            ay += p[i] * v[i].y;
            az += p[i] * v[i].z;
            aw += p[i] * v[i].w;
        }
        acc.x = ax; acc.y = ay; acc.z = az; acc.w = aw;
        m = m_new;
    }

    // Intra-block merge of the 4 wave states via LDS.
    __shared__ float sm[WAVES];
    __shared__ float sl[WAVES];
    __shared__ float sacc[WAVES][H_];
    if (lane == 0) { sm[wave] = m; sl[wave] = l; }
    ((float4*)&sacc[wave][0])[lane] = acc;   // columns 4*lane..4*lane+3
    __syncthreads();

    const float M  = fmaxf(fmaxf(sm[0], sm[1]), fmaxf(sm[2], sm[3]));
    const float w0 = __expf(sm[0] - M);
    const float w1 = __expf(sm[1] - M);
    const float w2 = __expf(sm[2] - M);
    const float w3 = __expf(sm[3] - M);
    const int t = threadIdx.x;               // thread t owns column t
    const float num = w0 * sacc[0][t] + w1 * sacc[1][t]
                    + w2 * sacc[2][t] + w3 * sacc[3][t];
    ws_acc[(size_t)blk * H_ + t] = num;
    if (t == 0) {
        ws_m[blk] = M;
        ws_l[blk] = w0 * sl[0] + w1 * sl[1] + w2 * sl[2] + w3 * sl[3];
    }
}

// Cross-chunk merge: one block per batch row, thread t owns column t.
__global__ __launch_bounds__(256) void pool_merge(
    const float* __restrict__ ws_acc, const float* __restrict__ ws_m,
    const float* __restrict__ ws_l, float* __restrict__ out)
{
    const int b = blockIdx.x;
    const int t = threadIdx.x;

    float M = -1e30f;
    #pragma unroll
    for (int c = 0; c < CHUNKS; ++c) M = fmaxf(M, ws_m[b * CHUNKS + c]);

    float den = 0.f, num = 0.f;
    #pragma unroll
    for (int c = 0; c < CHUNKS; ++c) {
        const float w = __expf(ws_m[b * CHUNKS + c] - M);
        den += w * ws_l[b * CHUNKS + c];
        num += w * ws_acc[(size_t)(b * CHUNKS + c) * H_ + t];
    }
    out[b * H_ + t] = num / den;
}

extern "C" void kernel_launch(void* const* d_in, const int* in_sizes, int n_in,
                              void* d_out, int out_size, void* d_ws, size_t ws_size,
                              hipStream_t stream) {
    const float* emb   = (const float*)d_in[0];  // [B,T,H] fp32
    const float* mask  = (const float*)d_in[1];  // [B,T]   fp32
    const float* query = (const float*)d_in[2];  // [H]     fp32
    float* out = (float*)d_out;                  // [B,H]   fp32

    // Workspace layout: acc[NBLK*H] | m[NBLK] | l[NBLK]  (~1 MB)
    float* ws_acc = (float*)d_ws;
    float* ws_m   = ws_acc + (size_t)NBLK * H_;
    float* ws_l   = ws_m + NBLK;

    pool_pass1<<<NBLK, 256, 0, stream>>>(emb, mask, query, ws_acc, ws_m, ws_l);
    pool_merge<<<B_, 256, 0, stream>>>(ws_acc, ws_m, ws_l, out);
}